// Round 5
// baseline (39481.119 us; speedup 1.0000x reference)
//
#include <hip/hip_runtime.h>
#include <math.h>

// ---------------------------------------------------------------------------
// CDDD decoder: persistent-kernel version (v5).
// One launch: 512 blocks x 256 threads (2 blocks/CU), device-scope spin
// barriers between phases. Weights via VMEM broadcast loads with explicit
// double-buffered groups (~26 loads in flight/wave). Activations in T4
// layout: buf[(k4*64+b)*4+c] == value[b][k4*4+c].
// ---------------------------------------------------------------------------

#define BATCH 64
#define NBLK  512
#define NTHR  256

__device__ __forceinline__ void fma4(float& acc, const float4 w, const float4 x) {
    acc = fmaf(w.x, x.x, acc);
    acc = fmaf(w.y, x.y, acc);
    acc = fmaf(w.z, x.z, acc);
    acc = fmaf(w.w, x.w, acc);
}

__device__ __forceinline__ float sigmoid_f(float x) {
    return 1.0f / (1.0f + expf(-x));
}

// Device-scope sense-free generation barrier. All blocks must be resident.
__device__ __forceinline__ void gbar(int* cnt, int* gen) {
    __syncthreads();
    if (threadIdx.x == 0) {
        int g = __hip_atomic_load(gen, __ATOMIC_RELAXED, __HIP_MEMORY_SCOPE_AGENT);
        int v = __hip_atomic_fetch_add(cnt, 1, __ATOMIC_ACQ_REL, __HIP_MEMORY_SCOPE_AGENT);
        if (v == NBLK - 1) {
            __hip_atomic_store(cnt, 0, __ATOMIC_RELAXED, __HIP_MEMORY_SCOPE_AGENT);
            __hip_atomic_store(gen, g + 1, __ATOMIC_RELEASE, __HIP_MEMORY_SCOPE_AGENT);
        } else {
            while (__hip_atomic_load(gen, __ATOMIC_ACQUIRE, __HIP_MEMORY_SCOPE_AGENT) == g) {
                __builtin_amdgcn_s_sleep(1);
            }
        }
    }
    __syncthreads();
}

// Double-buffered GEMV pipeline: CW columns x 3 gates, one quad (4 K-elems)
// per group. Two groups in flight -> ~2*(3*CW+1) outstanding loads.
template<int CW, bool EMB>
struct Pipe {
    const float* p[3][CW];
    const float* act;
    int qb, b;

    __device__ __forceinline__ void loadg(float4 w[3][CW], float4& a, int i) {
#pragma unroll
        for (int g = 0; g < 3; ++g)
#pragma unroll
            for (int c = 0; c < CW; ++c)
                w[g][c] = *(const float4*)(p[g][c] + 4 * i);
        if (EMB) a = ((const float4*)act)[qb + i];
        else     a = ((const float4*)act)[(qb + i) * 64 + b];
    }
    __device__ __forceinline__ void fmag(const float4 w[3][CW], const float4 a,
                                         float accR[CW], float accZ[CW], float accN[CW]) {
#pragma unroll
        for (int c = 0; c < CW; ++c) {
            fma4(accR[c], w[0][c], a);
            fma4(accZ[c], w[1][c], a);
            fma4(accN[c], w[2][c], a);
        }
    }
    // nq even, nq >= 2
    __device__ __forceinline__ void run(int nq, float accR[CW], float accZ[CW], float accN[CW]) {
        float4 wA[3][CW], wB[3][CW], aA, aB;
        loadg(wA, aA, 0);
        loadg(wB, aB, 1);
        int i = 0;
        for (; i + 2 < nq; i += 2) {
            fmag(wA, aA, accR, accZ, accN);
            loadg(wA, aA, i + 2);
            fmag(wB, aB, accR, accZ, accN);
            loadg(wB, aB, i + 3);
        }
        fmag(wA, aA, accR, accZ, accN);
        fmag(wB, aB, accR, accZ, accN);
    }
};

// One GRU layer phase. Block owns CW columns; KS waves split concat-K.
template<int IN, int H, int CW, int KS, bool L0P>
__device__ __forceinline__ void gru_phase(
    int bid, int tid,
    const float* xT4, const float* emb, const int* dec,
    const float* hin, float* hout,
    const float* w_ih, const float* w_hh,
    const float* b_ih, const float* b_hh, float* smem)
{
    constexpr int KT = IN + H;
    constexpr int KW = KT / KS;
    const int wid = tid >> 6;
    const int b   = tid & 63;
    const int j0  = bid * CW;
    const int e0  = __builtin_amdgcn_readfirstlane(wid * KW);
    const int e1  = e0 + KW;

    float accR[CW], accZ[CW], accNX[CW], accNH[CW];
#pragma unroll
    for (int c = 0; c < CW; ++c) { accR[c]=0.f; accZ[c]=0.f; accNX[c]=0.f; accNH[c]=0.f; }

    const int xs1 = e1 < IN ? e1 : IN;
    if (e0 < xs1) {
        Pipe<CW, L0P> P;
#pragma unroll
        for (int g = 0; g < 3; ++g)
#pragma unroll
            for (int c = 0; c < CW; ++c)
                P.p[g][c] = w_ih + (size_t)(g * H + j0 + c) * IN + e0;
        P.act = L0P ? (emb + dec[b] * 32) : xT4;
        P.qb = e0 / 4; P.b = b;
        P.run((xs1 - e0) / 4, accR, accZ, accNX);
    }
    const int hs0 = e0 > IN ? e0 : IN;
    if (hs0 < e1) {
        const int k0 = hs0 - IN;
        Pipe<CW, false> P;
#pragma unroll
        for (int g = 0; g < 3; ++g)
#pragma unroll
            for (int c = 0; c < CW; ++c)
                P.p[g][c] = w_hh + (size_t)(g * H + j0 + c) * H + k0;
        P.act = hin; P.qb = k0 / 4; P.b = b;
        P.run((e1 - hs0) / 4, accR, accZ, accNH);
    }

    float (*red)[CW][4][64] = (float(*)[CW][4][64])smem;   // [KS][CW][4][64]
#pragma unroll
    for (int c = 0; c < CW; ++c) {
        red[wid][c][0][b] = accR[c];
        red[wid][c][1][b] = accZ[c];
        red[wid][c][2][b] = accNX[c];
        red[wid][c][3][b] = accNH[c];
    }
    __syncthreads();
    if (tid < CW * 64) {
        const int c  = tid >> 6;
        const int bb = tid & 63;
        float R = 0.f, Z = 0.f, NX = 0.f, NH = 0.f;
#pragma unroll
        for (int k = 0; k < KS; ++k) {
            R  += red[k][c][0][bb];
            Z  += red[k][c][1][bb];
            NX += red[k][c][2][bb];
            NH += red[k][c][3][bb];
        }
        const int j = j0 + c;
        const float r  = sigmoid_f(R + b_ih[j]     + b_hh[j]);
        const float zg = sigmoid_f(Z + b_ih[j + H] + b_hh[j + H]);
        const float n  = tanhf(NX + b_ih[j + 2 * H] + r * (NH + b_hh[j + 2 * H]));
        const float hp = hin[((j >> 2) * 64 + bb) * 4 + (j & 3)];
        hout[((j >> 2) * 64 + bb) * 4 + (j & 3)] = (1.f - zg) * n + zg * hp;
    }
}

// Logits + argmax phase: blocks 0..63 each handle one batch row.
__device__ __forceinline__ void out_phase(
    int bid, int tid, const float* h2, const float* w_out,
    int* dec, int* out, int s, int max_len, float* smem)
{
    if (bid < BATCH) {
        float* hs = smem;          // 2048 floats
        float* lg = smem + 2048;   // 40 floats
        const int b = bid, wid = tid >> 6, lane = tid & 63;
        const float4* h4 = (const float4*)h2;
        ((float4*)hs)[tid]       = h4[tid * 64 + b];
        ((float4*)hs)[tid + 256] = h4[(tid + 256) * 64 + b];
        __syncthreads();
        const float4* hs4 = (const float4*)hs;
        for (int v = wid * 10; v < wid * 10 + 10; ++v) {
            const float4* w4 = (const float4*)(w_out + (size_t)v * 2048);
            float acc = 0.f;
#pragma unroll
            for (int it = 0; it < 8; ++it) {
                const int k4 = it * 64 + lane;
                fma4(acc, w4[k4], hs4[k4]);
            }
#pragma unroll
            for (int off = 32; off > 0; off >>= 1)
                acc += __shfl_down(acc, off, 64);
            if (lane == 0) lg[v] = acc;
        }
        __syncthreads();
        if (tid == 0) {
            float best = lg[0];
            int bi = 0;
#pragma unroll
            for (int v = 1; v < 40; ++v) {
                const float val = lg[v];
                if (val > best) { best = val; bi = v; }
            }
            dec[b] = bi;
            out[b * max_len + s] = bi;
        }
    }
}

__global__ void zero_bar_kernel(int* cnt, int* gen) {
    if (threadIdx.x == 0) { *cnt = 0; *gen = 0; }
}

__global__ __launch_bounds__(NTHR, 2) void decoder_kernel(
    const float* __restrict__ z, const float* __restrict__ emb,
    const float* __restrict__ fc_init_w, const float* __restrict__ fc_init_b,
    const float* __restrict__ fc_out_w,
    const float* __restrict__ w_ih0, const float* __restrict__ w_hh0,
    const float* __restrict__ b_ih0, const float* __restrict__ b_hh0,
    const float* __restrict__ w_ih1, const float* __restrict__ w_hh1,
    const float* __restrict__ b_ih1, const float* __restrict__ b_hh1,
    const float* __restrict__ w_ih2, const float* __restrict__ w_hh2,
    const float* __restrict__ b_ih2, const float* __restrict__ b_hh2,
    const int* __restrict__ start_tok,
    float* zT4, float* h0a, float* h0b, float* h1a, float* h1b,
    float* h2a, float* h2b, int* dec, int* cnt, int* gen,
    int* out, int max_len)
{
    __shared__ float smem[4096];   // 16 KB, aliased per phase
    const int bid = blockIdx.x;
    const int tid = threadIdx.x;

    // ---- Phase A: transpose z -> zT4; init dec ----
    if (bid == 0) {
        for (int i = tid; i < 8192; i += NTHR) {
            const int b = i >> 7, k4 = i & 127;
            ((float4*)zT4)[k4 * 64 + b] = ((const float4*)z)[b * 128 + k4];
        }
        if (tid < BATCH) dec[tid] = start_tok[0];
    }
    gbar(cnt, gen);

    // ---- Phase B: init_states GEMV (3584 rows = 512 blocks x 7) ----
    {
        const int wid = tid >> 6, b = tid & 63;
        for (int i = wid; i < 7; i += 4) {
            const int r = bid * 7 + i;
            const float4* w4 = (const float4*)(fc_init_w + (size_t)r * 512);
            const float4* z4 = (const float4*)zT4;
            float acc = 0.f;
#pragma unroll 4
            for (int k = 0; k < 128; ++k) fma4(acc, w4[k], z4[k * 64 + b]);
            acc += fc_init_b[r];
            float* dst; int j;
            if (r < 512)       { dst = h0a; j = r; }
            else if (r < 1536) { dst = h1a; j = r - 512; }
            else               { dst = h2a; j = r - 1536; }
            dst[((j >> 2) * 64 + b) * 4 + (j & 3)] = acc;
        }
    }
    gbar(cnt, gen);

    // ---- decode loop ----
    for (int s = 0; s < max_len; ++s) {
        const int pi = s & 1;
        const float* h0i = pi ? h0b : h0a;  float* h0o = pi ? h0a : h0b;
        const float* h1i = pi ? h1b : h1a;  float* h1o = pi ? h1a : h1b;
        const float* h2i = pi ? h2b : h2a;  float* h2o = pi ? h2a : h2b;

        // L0: 512 cols, 1 col/block, KSPLIT=4 over K=544
        gru_phase<32, 512, 1, 4, true>(bid, tid, nullptr, emb, dec,
                                       h0i, h0o, w_ih0, w_hh0, b_ih0, b_hh0, smem);
        gbar(cnt, gen);
        // L1: 1024 cols, 2 cols/block, KSPLIT=4 over K=1536
        gru_phase<512, 1024, 2, 4, false>(bid, tid, h0o, nullptr, nullptr,
                                          h1i, h1o, w_ih1, w_hh1, b_ih1, b_hh1, smem);
        gbar(cnt, gen);
        // L2: 2048 cols, 4 cols/block, KSPLIT=4 over K=3072
        gru_phase<1024, 2048, 4, 4, false>(bid, tid, h1o, nullptr, nullptr,
                                           h2i, h2o, w_ih2, w_hh2, b_ih2, b_hh2, smem);
        gbar(cnt, gen);
        // logits + argmax
        out_phase(bid, tid, h2o, fc_out_w, dec, out, s, max_len, smem);
        gbar(cnt, gen);
    }
}

extern "C" void kernel_launch(void* const* d_in, const int* in_sizes, int n_in,
                              void* d_out, int out_size, void* d_ws, size_t ws_size,
                              hipStream_t stream)
{
    const float* z         = (const float*)d_in[0];
    const float* emb       = (const float*)d_in[1];
    const float* fc_init_w = (const float*)d_in[2];
    const float* fc_init_b = (const float*)d_in[3];
    const float* fc_out_w  = (const float*)d_in[4];
    const float* w_ih0 = (const float*)d_in[5];
    const float* w_hh0 = (const float*)d_in[6];
    const float* b_ih0 = (const float*)d_in[7];
    const float* b_hh0 = (const float*)d_in[8];
    const float* w_ih1 = (const float*)d_in[9];
    const float* w_hh1 = (const float*)d_in[10];
    const float* b_ih1 = (const float*)d_in[11];
    const float* b_hh1 = (const float*)d_in[12];
    const float* w_ih2 = (const float*)d_in[13];
    const float* w_hh2 = (const float*)d_in[14];
    const float* b_ih2 = (const float*)d_in[15];
    const float* b_hh2 = (const float*)d_in[16];
    const int* start_tok = (const int*)d_in[18];

    char* ws = (char*)d_ws;
    float* zT4 = (float*)(ws + 0);                // 128KB
    float* h0a = (float*)(ws + 131072);           // 128KB
    float* h0b = (float*)(ws + 262144);
    float* h1a = (float*)(ws + 393216);           // 256KB
    float* h1b = (float*)(ws + 655360);
    float* h2a = (float*)(ws + 917504);           // 512KB
    float* h2b = (float*)(ws + 1441792);
    int*   dec = (int*)(ws + 1966080);
    int*   cnt = (int*)(ws + 1966336);
    int*   gen = (int*)(ws + 1966400);

    int* out = (int*)d_out;
    const int max_len = out_size / BATCH;   // 64

    zero_bar_kernel<<<1, 64, 0, stream>>>(cnt, gen);
    decoder_kernel<<<NBLK, NTHR, 0, stream>>>(
        z, emb, fc_init_w, fc_init_b, fc_out_w,
        w_ih0, w_hh0, b_ih0, b_hh0,
        w_ih1, w_hh1, b_ih1, b_hh1,
        w_ih2, w_hh2, b_ih2, b_hh2,
        start_tok, zT4, h0a, h0b, h1a, h1b, h2a, h2b,
        dec, cnt, gen, out, max_len);
}

// Round 6
// 16553.033 us; speedup vs baseline: 2.3851x; 2.3851x over previous
//
#include <hip/hip_runtime.h>
#include <math.h>

// ---------------------------------------------------------------------------
// CDDD decoder v6: 3-layer GRU (512/1024/2048) greedy decode, B=64, 64 steps.
// Multi-launch (graph-replayed). Key change vs r3/r5: weights are staged
// HBM->LDS with lane-distinct coalesced float4 loads (1KB/instr) in
// double-buffered TK=256 slabs, then consumed as same-address (broadcast)
// ds_read_b128 — broadcast VMEM loads (16B unique/instr) were the bottleneck.
// Activations stay in "T4" layout: buf[(k4*64+b)*4+c] == value[b][k4*4+c].
// ---------------------------------------------------------------------------

#define BATCH 64

__device__ __forceinline__ void fma4(float& acc, const float4 w, const float4 x) {
    acc = fmaf(w.x, x.x, acc);
    acc = fmaf(w.y, x.y, acc);
    acc = fmaf(w.z, x.z, acc);
    acc = fmaf(w.w, x.w, acc);
}

__device__ __forceinline__ float sigmoid_f(float x) {
    return 1.0f / (1.0f + expf(-x));
}

// Transpose z [64,512] -> zT4, and init dec[] with start token.
__global__ __launch_bounds__(256) void init_misc_kernel(
    const float* __restrict__ z, float* __restrict__ zT4,
    int* __restrict__ dec, const int* __restrict__ start_tok)
{
    int tid = blockIdx.x * 256 + threadIdx.x;   // 8192 threads: (b, k4)
    int b  = tid >> 7;
    int k4 = tid & 127;
    float4 v = ((const float4*)z)[b * 128 + k4];
    ((float4*)zT4)[k4 * 64 + b] = v;
    if (tid < BATCH) dec[tid] = start_tok[0];
}

// init_states = z @ fc_init_w.T + fc_init_b ; split into h0/h1/h2 (T4 layout).
__global__ __launch_bounds__(256) void init_h_kernel(
    const float* __restrict__ zT4, const float* __restrict__ w,
    const float* __restrict__ bias,
    float* __restrict__ h0, float* __restrict__ h1, float* __restrict__ h2)
{
    const int wave = threadIdx.x >> 6;
    const int b    = threadIdx.x & 63;
    const int r    = blockIdx.x * 4 + wave;      // 0..3583
    const float4* w4 = (const float4*)(w + (size_t)r * 512);
    const float4* z4 = (const float4*)zT4;
    float acc = 0.f;
#pragma unroll 8
    for (int k = 0; k < 128; ++k) fma4(acc, w4[k], z4[k * 64 + b]);
    acc += bias[r];
    float* dst; int j;
    if (r < 512)       { dst = h0; j = r; }
    else if (r < 1536) { dst = h1; j = r - 512; }
    else               { dst = h2; j = r - 1536; }
    dst[(((j >> 2) * 64 + b) << 2) + (j & 3)] = acc;
}

// Compute one staged slab: wave `wid` covers 8 quads (32 K-elems) of the
// TK=256 slab. Weight reads: wave-uniform address -> ds_read_b128 broadcast.
// Act reads: lane=batch coalesced float4 from the T4 buffer.
template<int CW>
__device__ __forceinline__ void slab_compute(
    const float (*__restrict__ wb)[256], const float* __restrict__ actT4,
    int slab_q0, int wid, int lane,
    float (&accR)[CW], float (&accZ)[CW], float (&accN)[CW])
{
    const int qb = wid * 8;
#pragma unroll
    for (int q8 = 0; q8 < 8; ++q8) {
        const int qq = qb + q8;
        const float4 a = ((const float4*)actT4)[(slab_q0 + qq) * 64 + lane];
#pragma unroll
        for (int c = 0; c < CW; ++c) {
            fma4(accR[c], ((const float4*)wb[0 * CW + c])[qq], a);
            fma4(accZ[c], ((const float4*)wb[1 * CW + c])[qq], a);
            fma4(accN[c], ((const float4*)wb[2 * CW + c])[qq], a);
        }
    }
}

// GRU layer step v6. Block: 512 thr = 8 waves, owns CW output columns.
// K processed in TK=256 slabs: NSX x-slabs (from w_ih) then NSH h-slabs
// (from w_hh), weights double-buffered through LDS.
// L0 (IN=32): x-part handled directly by wave 0 (per-lane emb rows), NSX=0.
template<int IN, int H, int CW, bool L0P>
__global__ __launch_bounds__(512, 4) void gru6_kernel(
    const float* __restrict__ xT4, const float* __restrict__ emb,
    const int* __restrict__ dec,
    const float* __restrict__ hin, float* __restrict__ hout,
    const float* __restrict__ w_ih, const float* __restrict__ w_hh,
    const float* __restrict__ b_ih, const float* __restrict__ b_hh)
{
    constexpr int NSX = IN / 256;      // 0 for L0 (IN=32)
    constexpr int NSH = H / 256;
    constexpr int NS  = NSX + NSH;
    constexpr int R   = 3 * CW;        // weight rows per slab

    __shared__ float wbuf[2][R][256];
    __shared__ float red[8][CW][4][64];

    const int tid  = threadIdx.x;
    const int wid  = tid >> 6;
    const int lane = tid & 63;
    const int j0   = blockIdx.x * CW;

    // stage-row pointer for slab s, row r (r = g*CW + c)
    auto srow = [&](int s, int r) -> const float* {
        const int g = r / CW, c = r % CW;
        if (s < NSX) return w_ih + ((size_t)g * H + j0 + c) * IN + s * 256;
        return w_hh + ((size_t)g * H + j0 + c) * H + (s - NSX) * 256;
    };

    float accR[CW], accZ[CW], accNX[CW], accNH[CW];
#pragma unroll
    for (int c = 0; c < CW; ++c) { accR[c] = 0.f; accZ[c] = 0.f; accNX[c] = 0.f; accNH[c] = 0.f; }

    const bool st0 = (wid < R);
    const bool st1 = (wid + 8 < R);

    // ---- prologue: stage slab 0 (issue loads, then overlap-able work, then write) ----
    float4 t0, t1;
    if (st0) t0 = ((const float4*)srow(0, wid))[lane];
    if (st1) t1 = ((const float4*)srow(0, wid + 8))[lane];

    // L0 x-part: wave 0 computes the full IN=32 contribution directly.
    if (L0P && wid == 0) {
        const int tok = dec[lane];
        const float4* xb = (const float4*)(emb + tok * 32);
#pragma unroll
        for (int q = 0; q < 8; ++q) {
            const float4 a = xb[q];
#pragma unroll
            for (int c = 0; c < CW; ++c) {
                fma4(accR[c],  *(const float4*)(w_ih + ((size_t)0 * H + j0 + c) * 32 + q * 4), a);
                fma4(accZ[c],  *(const float4*)(w_ih + ((size_t)1 * H + j0 + c) * 32 + q * 4), a);
                fma4(accNX[c], *(const float4*)(w_ih + ((size_t)2 * H + j0 + c) * 32 + q * 4), a);
            }
        }
    }

    if (st0) ((float4*)wbuf[0][wid])[lane] = t0;
    if (st1) ((float4*)wbuf[0][wid + 8])[lane] = t1;
    __syncthreads();

    // ---- slab loop ----
    for (int s = 0; s < NS; ++s) {
        const int cur = s & 1;
        const bool more = (s + 1 < NS);
        if (more) {
            if (st0) t0 = ((const float4*)srow(s + 1, wid))[lane];
            if (st1) t1 = ((const float4*)srow(s + 1, wid + 8))[lane];
        }
        if (s < NSX)
            slab_compute<CW>(wbuf[cur], xT4, s * 64, wid, lane, accR, accZ, accNX);
        else
            slab_compute<CW>(wbuf[cur], hin, (s - NSX) * 64, wid, lane, accR, accZ, accNH);
        if (more) {
            if (st0) ((float4*)wbuf[cur ^ 1][wid])[lane] = t0;
            if (st1) ((float4*)wbuf[cur ^ 1][wid + 8])[lane] = t1;
        }
        __syncthreads();
    }

    // ---- reduce across the 8 waves, finish gates ----
#pragma unroll
    for (int c = 0; c < CW; ++c) {
        red[wid][c][0][lane] = accR[c];
        red[wid][c][1][lane] = accZ[c];
        red[wid][c][2][lane] = accNX[c];
        red[wid][c][3][lane] = accNH[c];
    }
    __syncthreads();

    if (tid < CW * 64) {
        const int c  = tid >> 6;
        const int bb = tid & 63;
        float Rg = 0.f, Zg = 0.f, NX = 0.f, NH = 0.f;
#pragma unroll
        for (int k = 0; k < 8; ++k) {
            Rg += red[k][c][0][bb];
            Zg += red[k][c][1][bb];
            NX += red[k][c][2][bb];
            NH += red[k][c][3][bb];
        }
        const int j = j0 + c;
        const float r  = sigmoid_f(Rg + b_ih[j]     + b_hh[j]);
        const float zg = sigmoid_f(Zg + b_ih[j + H] + b_hh[j + H]);
        const float n  = tanhf(NX + b_ih[j + 2 * H] + r * (NH + b_hh[j + 2 * H]));
        const float hp = hin[(((j >> 2) * 64 + bb) << 2) + (j & 3)];
        hout[(((j >> 2) * 64 + bb) << 2) + (j & 3)] = (1.f - zg) * n + zg * hp;
    }
}

// Fused logits + argmax: one block per batch element, 512 threads = 8 waves.
__global__ __launch_bounds__(512) void out_kernel(
    const float* __restrict__ h2T4, const float* __restrict__ w_out,
    int* __restrict__ dec, int* __restrict__ out, int s, int max_len)
{
    __shared__ float hs[2048];
    __shared__ float lg[40];
    const int b    = blockIdx.x;
    const int tid  = threadIdx.x;
    const int wave = tid >> 6;    // 0..7
    const int lane = tid & 63;

    const float4* h4 = (const float4*)h2T4;
    ((float4*)hs)[tid] = h4[tid * 64 + b];    // 512 threads x 1 quad = 2048 f32
    __syncthreads();

    const float4* hs4 = (const float4*)hs;
#pragma unroll
    for (int v = wave * 5; v < wave * 5 + 5; ++v) {
        const float4* w4 = (const float4*)(w_out + (size_t)v * 2048);
        float acc = 0.f;
#pragma unroll
        for (int it = 0; it < 8; ++it) {
            const int k4 = it * 64 + lane;
            fma4(acc, w4[k4], hs4[k4]);
        }
#pragma unroll
        for (int off = 32; off > 0; off >>= 1)
            acc += __shfl_down(acc, off, 64);
        if (lane == 0) lg[v] = acc;
    }
    __syncthreads();

    if (tid == 0) {
        float best = lg[0];
        int bi = 0;
#pragma unroll
        for (int v = 1; v < 40; ++v) {
            const float val = lg[v];
            if (val > best) { best = val; bi = v; }
        }
        dec[b] = bi;
        out[b * max_len + s] = bi;
    }
}

extern "C" void kernel_launch(void* const* d_in, const int* in_sizes, int n_in,
                              void* d_out, int out_size, void* d_ws, size_t ws_size,
                              hipStream_t stream)
{
    const float* z         = (const float*)d_in[0];
    const float* emb       = (const float*)d_in[1];
    const float* fc_init_w = (const float*)d_in[2];
    const float* fc_init_b = (const float*)d_in[3];
    const float* fc_out_w  = (const float*)d_in[4];
    const float* w_ih0 = (const float*)d_in[5];
    const float* w_hh0 = (const float*)d_in[6];
    const float* b_ih0 = (const float*)d_in[7];
    const float* b_hh0 = (const float*)d_in[8];
    const float* w_ih1 = (const float*)d_in[9];
    const float* w_hh1 = (const float*)d_in[10];
    const float* b_ih1 = (const float*)d_in[11];
    const float* b_hh1 = (const float*)d_in[12];
    const float* w_ih2 = (const float*)d_in[13];
    const float* w_hh2 = (const float*)d_in[14];
    const float* b_ih2 = (const float*)d_in[15];
    const float* b_hh2 = (const float*)d_in[16];
    const int* start_tok = (const int*)d_in[18];

    // workspace layout (bytes)
    char* ws = (char*)d_ws;
    float* zT4    = (float*)(ws + 0);                                  // 128KB
    float* h0b[2] = { (float*)(ws + 131072), (float*)(ws + 262144) };  // 128KB each
    float* h1b[2] = { (float*)(ws + 393216), (float*)(ws + 655360) };  // 256KB each
    float* h2b[2] = { (float*)(ws + 917504), (float*)(ws + 1441792) }; // 512KB each
    int*   dec    = (int*)(ws + 1966080);

    int* out = (int*)d_out;
    const int max_len = out_size / BATCH;   // 64

    init_misc_kernel<<<32, 256, 0, stream>>>(z, zT4, dec, start_tok);
    init_h_kernel<<<896, 256, 0, stream>>>(zT4, fc_init_w, fc_init_b,
                                           h0b[0], h1b[0], h2b[0]);

    for (int s = 0; s < max_len; ++s) {
        const int pi = s & 1, po = pi ^ 1;
        // L0: 512 cols, CW=2 -> 256 blocks (x-part direct from emb)
        gru6_kernel<32, 512, 2, true><<<256, 512, 0, stream>>>(
            nullptr, emb, dec, h0b[pi], h0b[po], w_ih0, w_hh0, b_ih0, b_hh0);
        // L1: 1024 cols, CW=4 -> 256 blocks (NSX=2, NSH=4)
        gru6_kernel<512, 1024, 4, false><<<256, 512, 0, stream>>>(
            h0b[po], nullptr, nullptr, h1b[pi], h1b[po], w_ih1, w_hh1, b_ih1, b_hh1);
        // L2: 2048 cols, CW=4 -> 512 blocks (NSX=4, NSH=8)
        gru6_kernel<1024, 2048, 4, false><<<512, 512, 0, stream>>>(
            h1b[po], nullptr, nullptr, h2b[pi], h2b[po], w_ih2, w_hh2, b_ih2, b_hh2);
        // logits + argmax fused: 64 blocks (one per batch row), 512 threads
        out_kernel<<<64, 512, 0, stream>>>(h2b[po], fc_out_w, dec, out, s, max_len);
    }
}

// Round 7
// 7931.458 us; speedup vs baseline: 4.9778x; 2.0870x over previous
//
#include <hip/hip_runtime.h>
#include <math.h>

// ---------------------------------------------------------------------------
// CDDD decoder v7: 3-layer GRU (512/1024/2048) greedy decode, B=64, 64 steps.
//
// Core fix vs rounds 1-6: the 93.6MB/step weight stream was consumed via
// BROADCAST loads (16B unique data per instruction, VMEM or LDS) -> pipe-
// bound at ~10x the VALU floor. v7 flips the GEMV: lane = output column,
// 8x8 (batch x col) register tile per lane, wave = 64 batches x 64 cols.
// Weights: pre-transposed once per call into ws as [colchunk64][k][64],
// streamed with lane-distinct coalesced b128 loads (256B unique/instr).
// Activations: tiny, staged to LDS once per block, broadcast reads (cheap).
// K split across blocks with x|h-boundary-aligned slices (keeps the GRU
// n-gate's x-part and h-part separable); partial sums combined + gate math
// in a small fused kernel. Activation interchange layout stays "T4":
//   buf[(q*64+b)*4+c] == value[b][q*4+c].
//
// Fallback: if ws_size is too small for the transposed weights, run the
// (passing) round-3 broadcast path.
// ---------------------------------------------------------------------------

#define BATCH 64

__device__ __forceinline__ float sigmoid_f(float x) { return 1.0f / (1.0f + expf(-x)); }

__device__ __forceinline__ void fma4(float& acc, const float4 w, const float4 x) {
    acc = fmaf(w.x, x.x, acc);
    acc = fmaf(w.y, x.y, acc);
    acc = fmaf(w.z, x.z, acc);
    acc = fmaf(w.w, x.w, acc);
}

// ---------------------------------------------------------------------------
// setup kernels
// ---------------------------------------------------------------------------

// Transpose z [64,512] -> zT4 (T4), init dec[], init embT for start token.
__global__ __launch_bounds__(256) void init_misc_kernel(
    const float* __restrict__ z, float* __restrict__ zT4,
    int* __restrict__ dec, const int* __restrict__ start_tok,
    const float* __restrict__ emb, float* __restrict__ embT)
{
    int tid = blockIdx.x * 256 + threadIdx.x;   // 8192 threads: (b, k4)
    int b  = tid >> 7;
    int k4 = tid & 127;
    ((float4*)zT4)[k4 * 64 + b] = ((const float4*)z)[b * 128 + k4];
    if (tid < BATCH) dec[tid] = start_tok[0];
    if (tid < 512) {
        int q = tid >> 6, bb = tid & 63;
        ((float4*)embT)[q * 64 + bb] = ((const float4*)(emb + start_tok[0] * 32))[q];
    }
}

// init_states = z @ fc_init_w.T + fc_init_b ; split into h0/h1/h2 (T4).
__global__ __launch_bounds__(256) void init_h_kernel(
    const float* __restrict__ zT4, const float* __restrict__ w,
    const float* __restrict__ bias,
    float* __restrict__ h0, float* __restrict__ h1, float* __restrict__ h2)
{
    const int wave = threadIdx.x >> 6;
    const int b    = threadIdx.x & 63;
    const int r    = blockIdx.x * 4 + wave;      // 0..3583
    const float4* w4 = (const float4*)(w + (size_t)r * 512);
    const float4* z4 = (const float4*)zT4;
    float acc = 0.f;
#pragma unroll 8
    for (int k = 0; k < 128; ++k) fma4(acc, w4[k], z4[k * 64 + b]);
    acc += bias[r];
    float* dst; int j;
    if (r < 512)       { dst = h0; j = r; }
    else if (r < 1536) { dst = h1; j = r - 512; }
    else               { dst = h2; j = r - 1536; }
    dst[(((j >> 2) * 64 + b) << 2) + (j & 3)] = acc;
}

// Tile-transpose W [NR][NC] row-major into O chunks: for row r, col k:
//   O[((r/64)*Ktot + koff + k)*64 + (r%64)] = W[r*NC + k]
// Grid: (NR/64, ceil(NC/64)); NR multiple of 64, NC multiple of 4.
__global__ __launch_bounds__(256) void transpose_kernel(
    const float* __restrict__ W, float* __restrict__ O,
    int NC, int Ktot, int koff)
{
    __shared__ float t[64][65];
    const int rb  = blockIdx.x * 64;
    const int kb  = blockIdx.y * 64;
    const int tid = threadIdx.x;
    const int r0  = tid >> 4;   // 0..15
    const int kq  = tid & 15;   // 0..15
    if (kb + kq * 4 < NC) {
#pragma unroll
        for (int rr = r0; rr < 64; rr += 16) {
            float4 v = *(const float4*)&W[(size_t)(rb + rr) * NC + kb + kq * 4];
            t[rr][kq * 4 + 0] = v.x;
            t[rr][kq * 4 + 1] = v.y;
            t[rr][kq * 4 + 2] = v.z;
            t[rr][kq * 4 + 3] = v.w;
        }
    }
    __syncthreads();
    const int k0 = tid >> 4;
    const int rq = tid & 15;
#pragma unroll
    for (int kk = k0; kk < 64; kk += 16) {
        if (kb + kk < NC) {
            float4 v = make_float4(t[rq * 4 + 0][kk], t[rq * 4 + 1][kk],
                                   t[rq * 4 + 2][kk], t[rq * 4 + 3][kk]);
            *(float4*)&O[((size_t)(rb >> 6) * Ktot + koff + kb + kk) * 64 + rq * 4] = v;
        }
    }
}

// ---------------------------------------------------------------------------
// v7 GEMV: block = 192 thr (3 waves), each wave one 64-col chunk;
// wave tile = 64 batches x 64 cols; lane tile 8b x 8j.
// Grid: (3H/192, KSX+KSH). Slice ks covers quads [q0,q1) of the concat-K,
// never straddling the x|h boundary QX.
// ---------------------------------------------------------------------------

#define FMA8(WA, WB, XS, bi) { \
    acc[bi][0].x = fmaf(WA.x, XS, acc[bi][0].x); \
    acc[bi][0].y = fmaf(WA.y, XS, acc[bi][0].y); \
    acc[bi][0].z = fmaf(WA.z, XS, acc[bi][0].z); \
    acc[bi][0].w = fmaf(WA.w, XS, acc[bi][0].w); \
    acc[bi][1].x = fmaf(WB.x, XS, acc[bi][1].x); \
    acc[bi][1].y = fmaf(WB.y, XS, acc[bi][1].y); \
    acc[bi][1].z = fmaf(WB.z, XS, acc[bi][1].z); \
    acc[bi][1].w = fmaf(WB.w, XS, acc[bi][1].w); \
}

#define KSTEP(WA, WB, KO) { \
    const float4 xa = xr[(k + KO) * 16 + bg * 2]; \
    const float4 xb = xr[(k + KO) * 16 + bg * 2 + 1]; \
    FMA8(WA, WB, xa.x, 0) FMA8(WA, WB, xa.y, 1) \
    FMA8(WA, WB, xa.z, 2) FMA8(WA, WB, xa.w, 3) \
    FMA8(WA, WB, xb.x, 4) FMA8(WA, WB, xb.y, 5) \
    FMA8(WA, WB, xb.z, 6) FMA8(WA, WB, xb.w, 7) \
}

#define ACOMP(bi, jj) ((jj & 3) == 0 ? acc[bi][(jj) >> 2].x : \
                       (jj & 3) == 1 ? acc[bi][(jj) >> 2].y : \
                       (jj & 3) == 2 ? acc[bi][(jj) >> 2].z : acc[bi][(jj) >> 2].w)

template<int QX, int QTOT, int MAXQ, int KSX, int KSH>
__global__ __launch_bounds__(192, 2) void gemv_kernel(
    const float* __restrict__ xA,   // T4 source, quads [0, QX)
    const float* __restrict__ xB,   // T4 source, quads [QX, QTOT)
    const float* __restrict__ wT,   // [colchunk][QTOT*4][64]
    float* __restrict__ P)          // [KS][3H][64]
{
    __shared__ float xlds[MAXQ * 256];
    const int tid  = threadIdx.x;
    const int wid  = tid / 64;
    const int lane = tid & 63;
    const int cb   = blockIdx.x;
    const int ks   = blockIdx.y;
    const int NH3  = gridDim.x * 192;

    int q0, q1;
    if (ks < KSX) { q0 = (QX * ks) / KSX; q1 = (QX * (ks + 1)) / KSX; }
    else {
        const int t = ks - KSX;
        q0 = QX + ((QTOT - QX) * t) / KSH;
        q1 = QX + ((QTOT - QX) * (t + 1)) / KSH;
    }

    // stage x quads [q0,q1) into LDS as [k_local][64 b]
    for (int q = q0 + wid; q < q1; q += 3) {
        const float4 v = (q < QX) ? ((const float4*)xA)[q * 64 + lane]
                                  : ((const float4*)xB)[(q - QX) * 64 + lane];
        const int ql = q - q0;
        xlds[(ql * 4 + 0) * 64 + lane] = v.x;
        xlds[(ql * 4 + 1) * 64 + lane] = v.y;
        xlds[(ql * 4 + 2) * 64 + lane] = v.z;
        xlds[(ql * 4 + 3) * 64 + lane] = v.w;
    }
    __syncthreads();

    const int jg = lane & 7;     // col octet within the wave's 64 cols
    const int bg = lane >> 3;    // batch octet
    const int nk = (q1 - q0) * 4;
    const float4* __restrict__ wr =
        (const float4*)(wT + ((size_t)(cb * 3 + wid) * QTOT * 4 + (size_t)q0 * 4) * 64);
    const float4* __restrict__ xr = (const float4*)xlds;

    float4 acc[8][2];
#pragma unroll
    for (int i = 0; i < 8; ++i) {
        acc[i][0] = make_float4(0.f, 0.f, 0.f, 0.f);
        acc[i][1] = make_float4(0.f, 0.f, 0.f, 0.f);
    }

    // 4-deep k software pipeline on the weight stream
    float4 wa0 = wr[jg * 2],      wb0 = wr[jg * 2 + 1];
    float4 wa1 = wr[16 + jg * 2], wb1 = wr[16 + jg * 2 + 1];
    float4 wa2 = wr[32 + jg * 2], wb2 = wr[32 + jg * 2 + 1];
    float4 wa3 = wr[48 + jg * 2], wb3 = wr[48 + jg * 2 + 1];

    for (int k = 0; k < nk; k += 4) {
        float4 na0, nb0, na1, nb1, na2, nb2, na3, nb3;
        const bool pf = (k + 8 <= nk);
        if (pf) {
            na0 = wr[(k + 4) * 16 + jg * 2]; nb0 = wr[(k + 4) * 16 + jg * 2 + 1];
            na1 = wr[(k + 5) * 16 + jg * 2]; nb1 = wr[(k + 5) * 16 + jg * 2 + 1];
            na2 = wr[(k + 6) * 16 + jg * 2]; nb2 = wr[(k + 6) * 16 + jg * 2 + 1];
            na3 = wr[(k + 7) * 16 + jg * 2]; nb3 = wr[(k + 7) * 16 + jg * 2 + 1];
        }
        KSTEP(wa0, wb0, 0) KSTEP(wa1, wb1, 1) KSTEP(wa2, wb2, 2) KSTEP(wa3, wb3, 3)
        if (pf) {
            wa0 = na0; wb0 = nb0; wa1 = na1; wb1 = nb1;
            wa2 = na2; wb2 = nb2; wa3 = na3; wb3 = nb3;
        }
    }

    // write partial tile: P[ks][col][b], float4 over b
    float* __restrict__ Pw =
        P + ((size_t)ks * NH3 + (size_t)(cb * 192 + wid * 64 + jg * 8)) * 64 + bg * 8;
#pragma unroll
    for (int jj = 0; jj < 8; ++jj) {
        const float4 lo = make_float4(ACOMP(0, jj), ACOMP(1, jj), ACOMP(2, jj), ACOMP(3, jj));
        const float4 hi = make_float4(ACOMP(4, jj), ACOMP(5, jj), ACOMP(6, jj), ACOMP(7, jj));
        *(float4*)&Pw[jj * 64]     = lo;
        *(float4*)&Pw[jj * 64 + 4] = hi;
    }
}

// Combine partials + GRU gate math; h updated in place (T4 layout).
template<int H, int KSX, int KS>
__global__ __launch_bounds__(256) void combine_kernel(
    const float* __restrict__ P,
    const float* __restrict__ b_ih, const float* __restrict__ b_hh,
    float* __restrict__ h)
{
    const int gid = blockIdx.x * 256 + threadIdx.x;
    const int b = gid & 63;
    const int j = gid >> 6;
    float R = 0.f, Z = 0.f, NX = 0.f, NH = 0.f;
#pragma unroll
    for (int s = 0; s < KS; ++s) {
        const float* Ps = P + (size_t)s * (3 * H * 64);
        R += Ps[(0 * H + j) * 64 + b];
        Z += Ps[(1 * H + j) * 64 + b];
        const float nv = Ps[(2 * H + j) * 64 + b];
        if (s < KSX) NX += nv; else NH += nv;
    }
    const float r  = sigmoid_f(R + b_ih[j] + b_hh[j]);
    const float zg = sigmoid_f(Z + b_ih[H + j] + b_hh[H + j]);
    const float n  = tanhf(NX + b_ih[2 * H + j] + r * (NH + b_hh[2 * H + j]));
    const int idx = ((j >> 2) * 64 + b) * 4 + (j & 3);
    const float hp = h[idx];
    h[idx] = (1.f - zg) * n + zg * hp;
}

// Fused logits + argmax + next-token emb staging. One block per batch row.
__global__ __launch_bounds__(512) void out_kernel(
    const float* __restrict__ h2T4, const float* __restrict__ w_out,
    int* __restrict__ dec, int* __restrict__ out, int s, int max_len,
    const float* __restrict__ emb, float* __restrict__ embT)
{
    __shared__ float hs[2048];
    __shared__ float lg[40];
    __shared__ int stok;
    const int b    = blockIdx.x;
    const int tid  = threadIdx.x;
    const int wave = tid >> 6;
    const int lane = tid & 63;

    const float4* h4 = (const float4*)h2T4;
    ((float4*)hs)[tid] = h4[tid * 64 + b];
    __syncthreads();

    const float4* hs4 = (const float4*)hs;
#pragma unroll
    for (int v = wave * 5; v < wave * 5 + 5; ++v) {
        const float4* w4 = (const float4*)(w_out + (size_t)v * 2048);
        float acc = 0.f;
#pragma unroll
        for (int it = 0; it < 8; ++it) {
            const int k4 = it * 64 + lane;
            fma4(acc, w4[k4], hs4[k4]);
        }
#pragma unroll
        for (int off = 32; off > 0; off >>= 1)
            acc += __shfl_down(acc, off, 64);
        if (lane == 0) lg[v] = acc;
    }
    __syncthreads();

    if (tid == 0) {
        float best = lg[0];
        int bi = 0;
#pragma unroll
        for (int v = 1; v < 40; ++v) {
            const float val = lg[v];
            if (val > best) { best = val; bi = v; }
        }
        dec[b] = bi;
        out[b * max_len + s] = bi;
        stok = bi;
    }
    __syncthreads();
    if (tid < 8) {
        ((float4*)embT)[tid * 64 + b] = ((const float4*)(emb + stok * 32))[tid];
    }
}

// ---------------------------------------------------------------------------
// Fallback (round-3, proven): broadcast-load GRU kernel.
// ---------------------------------------------------------------------------
template<int IN, int H, int C, bool L0>
__global__ __launch_bounds__(512) void gru2_kernel(
    const float* __restrict__ xT4,
    const float* __restrict__ emb, const int* __restrict__ dec,
    const float* __restrict__ hT4_in, float* __restrict__ hT4_out,
    const float* __restrict__ w_ih, const float* __restrict__ w_hh,
    const float* __restrict__ b_ih, const float* __restrict__ b_hh)
{
    constexpr int Q  = (IN + H) / 4;
    constexpr int QX = IN / 4;
    constexpr int QW = Q / 8;

    const int tid  = threadIdx.x;
    const int wave = tid >> 6;
    const int b    = tid & 63;
    const int j0   = blockIdx.x * C;
    const int q0 = wave * QW;
    const int q1 = q0 + QW;

    float accR[C], accZ[C], accNX[C], accNH[C];
#pragma unroll
    for (int c = 0; c < C; ++c) { accR[c]=0.f; accZ[c]=0.f; accNX[c]=0.f; accNH[c]=0.f; }

    {
        const int xe = (q1 < QX) ? q1 : QX;
        if (q0 < xe) {
            const float4* xsrc;
            if (L0) { xsrc = (const float4*)(emb + dec[b] * 32); }
            else    { xsrc = (const float4*)xT4; }
            for (int q = q0; q < xe; ++q) {
                const float4 x = L0 ? xsrc[q] : xsrc[q * 64 + b];
#pragma unroll
                for (int c = 0; c < C; ++c) {
                    const int j = j0 + c;
                    fma4(accR[c],  *(const float4*)(w_ih + ((size_t)j * IN) + 4*q), x);
                    fma4(accZ[c],  *(const float4*)(w_ih + ((size_t)(j + H) * IN) + 4*q), x);
                    fma4(accNX[c], *(const float4*)(w_ih + ((size_t)(j + 2*H) * IN) + 4*q), x);
                }
            }
        }
    }
    {
        const int hs0 = (q0 > QX) ? q0 : QX;
        if (hs0 < q1) {
            const float4* h4 = (const float4*)hT4_in;
#pragma unroll 2
            for (int q = hs0; q < q1; ++q) {
                const int qh = q - QX;
                const float4 hv = h4[qh * 64 + b];
#pragma unroll
                for (int c = 0; c < C; ++c) {
                    const int j = j0 + c;
                    fma4(accR[c],  *(const float4*)(w_hh + ((size_t)j * H) + 4*qh), hv);
                    fma4(accZ[c],  *(const float4*)(w_hh + ((size_t)(j + H) * H) + 4*qh), hv);
                    fma4(accNH[c], *(const float4*)(w_hh + ((size_t)(j + 2*H) * H) + 4*qh), hv);
                }
            }
        }
    }

    __shared__ float red[8][C][4][64];
#pragma unroll
    for (int c = 0; c < C; ++c) {
        red[wave][c][0][b] = accR[c];
        red[wave][c][1][b] = accZ[c];
        red[wave][c][2][b] = accNX[c];
        red[wave][c][3][b] = accNH[c];
    }
    __syncthreads();

    if (tid < C * 64) {
        const int c  = tid >> 6;
        const int bb = tid & 63;
        float R = 0.f, Z = 0.f, NX = 0.f, NH = 0.f;
#pragma unroll
        for (int w = 0; w < 8; ++w) {
            R += red[w][c][0][bb]; Z += red[w][c][1][bb];
            NX += red[w][c][2][bb]; NH += red[w][c][3][bb];
        }
        const int j = j0 + c;
        const float r  = sigmoid_f(R + b_ih[j]     + b_hh[j]);
        const float zg = sigmoid_f(Z + b_ih[j + H] + b_hh[j + H]);
        const float n  = tanhf(NX + b_ih[j + 2 * H] + r * (NH + b_hh[j + 2 * H]));
        const float hp = hT4_in[(((j >> 2) * 64 + bb) << 2) + (j & 3)];
        hT4_out[(((j >> 2) * 64 + bb) << 2) + (j & 3)] = (1.f - zg) * n + zg * hp;
    }
}

// ---------------------------------------------------------------------------
// host
// ---------------------------------------------------------------------------
extern "C" void kernel_launch(void* const* d_in, const int* in_sizes, int n_in,
                              void* d_out, int out_size, void* d_ws, size_t ws_size,
                              hipStream_t stream)
{
    const float* z         = (const float*)d_in[0];
    const float* emb       = (const float*)d_in[1];
    const float* fc_init_w = (const float*)d_in[2];
    const float* fc_init_b = (const float*)d_in[3];
    const float* fc_out_w  = (const float*)d_in[4];
    const float* w_ih0 = (const float*)d_in[5];
    const float* w_hh0 = (const float*)d_in[6];
    const float* b_ih0 = (const float*)d_in[7];
    const float* b_hh0 = (const float*)d_in[8];
    const float* w_ih1 = (const float*)d_in[9];
    const float* w_hh1 = (const float*)d_in[10];
    const float* b_ih1 = (const float*)d_in[11];
    const float* b_hh1 = (const float*)d_in[12];
    const float* w_ih2 = (const float*)d_in[13];
    const float* w_hh2 = (const float*)d_in[14];
    const float* b_ih2 = (const float*)d_in[15];
    const float* b_hh2 = (const float*)d_in[16];
    const int* start_tok = (const int*)d_in[18];

    int* out = (int*)d_out;
    const int max_len = out_size / BATCH;   // 64
    char* ws = (char*)d_ws;

    const size_t NEED = 123937024;   // see offsets below

    if (ws_size >= NEED) {
        // -------- fast path: transposed-weight GEMV --------
        float* wT0  = (float*)(ws + 0);           //  3,342,336 B  [544 k][1536]
        float* wT1  = (float*)(ws + 3342336);     // 18,874,368 B  [1536][3072]
        float* wT2  = (float*)(ws + 22216704);    // 75,497,472 B  [3072][6144]
        float* P    = (float*)(ws + 97714176);    // 25,165,824 B  partials
        float* zT4  = (float*)(ws + 122880000);   //    131,072 B
        float* h0   = (float*)(ws + 123011072);   //    131,072 B
        float* h1   = (float*)(ws + 123142144);   //    262,144 B
        float* h2   = (float*)(ws + 123404288);   //    524,288 B
        float* embT = (float*)(ws + 123928576);   //      8,192 B
        int*   dec  = (int*)  (ws + 123936768);   //        256 B

        // weight transposes (once per call)
        transpose_kernel<<<dim3(24, 1),  256, 0, stream>>>(w_ih0, wT0, 32,   544,  0);
        transpose_kernel<<<dim3(24, 8),  256, 0, stream>>>(w_hh0, wT0, 512,  544,  32);
        transpose_kernel<<<dim3(48, 8),  256, 0, stream>>>(w_ih1, wT1, 512,  1536, 0);
        transpose_kernel<<<dim3(48, 16), 256, 0, stream>>>(w_hh1, wT1, 1024, 1536, 512);
        transpose_kernel<<<dim3(96, 16), 256, 0, stream>>>(w_ih2, wT2, 1024, 3072, 0);
        transpose_kernel<<<dim3(96, 32), 256, 0, stream>>>(w_hh2, wT2, 2048, 3072, 1024);

        init_misc_kernel<<<32, 256, 0, stream>>>(z, zT4, dec, start_tok, emb, embT);
        init_h_kernel<<<896, 256, 0, stream>>>(zT4, fc_init_w, fc_init_b, h0, h1, h2);

        for (int s = 0; s < max_len; ++s) {
            // L0: QX=8 quads (emb), QTOT=136; grid (8, 1+31)=256
            gemv_kernel<8, 136, 8, 1, 31><<<dim3(8, 32), 192, 0, stream>>>(embT, h0, wT0, P);
            combine_kernel<512, 1, 32><<<128, 256, 0, stream>>>(P, b_ih0, b_hh0, h0);
            // L1: QX=128, QTOT=384; grid (16, 11+21)=512
            gemv_kernel<128, 384, 13, 11, 21><<<dim3(16, 32), 192, 0, stream>>>(h0, h1, wT1, P);
            combine_kernel<1024, 11, 32><<<256, 256, 0, stream>>>(P, b_ih1, b_hh1, h1);
            // L2: QX=256, QTOT=768; grid (32, 5+11)=512
            gemv_kernel<256, 768, 52, 5, 11><<<dim3(32, 16), 192, 0, stream>>>(h1, h2, wT2, P);
            combine_kernel<2048, 5, 16><<<512, 256, 0, stream>>>(P, b_ih2, b_hh2, h2);
            out_kernel<<<64, 512, 0, stream>>>(h2, fc_out_w, dec, out, s, max_len, emb, embT);
        }
    } else {
        // -------- fallback: round-3 path --------
        float* zT4    = (float*)(ws + 0);
        float* h0b[2] = { (float*)(ws + 131072), (float*)(ws + 262144) };
        float* h1b[2] = { (float*)(ws + 393216), (float*)(ws + 655360) };
        float* h2b[2] = { (float*)(ws + 917504), (float*)(ws + 1441792) };
        int*   dec    = (int*)(ws + 1966080);
        float* embT   = (float*)(ws + 1966336);

        init_misc_kernel<<<32, 256, 0, stream>>>(z, zT4, dec, start_tok, emb, embT);
        init_h_kernel<<<896, 256, 0, stream>>>(zT4, fc_init_w, fc_init_b,
                                               h0b[0], h1b[0], h2b[0]);
        for (int s = 0; s < max_len; ++s) {
            const int pi = s & 1, po = pi ^ 1;
            gru2_kernel<32, 512, 2, true><<<256, 512, 0, stream>>>(
                nullptr, emb, dec, h0b[pi], h0b[po], w_ih0, w_hh0, b_ih0, b_hh0);
            gru2_kernel<512, 1024, 4, false><<<256, 512, 0, stream>>>(
                h0b[po], nullptr, nullptr, h1b[pi], h1b[po], w_ih1, w_hh1, b_ih1, b_hh1);
            gru2_kernel<1024, 2048, 4, false><<<512, 512, 0, stream>>>(
                h1b[po], nullptr, nullptr, h2b[pi], h2b[po], w_ih2, w_hh2, b_ih2, b_hh2);
            out_kernel<<<64, 512, 0, stream>>>(h2b[po], fc_out_w, dec, out, s, max_len,
                                               emb, embT);
        }
    }
}